// Round 14
// baseline (1061.752 us; speedup 1.0000x reference)
//
#include <hip/hip_runtime.h>

#define D 128
#define TILE_M 64
#define BS_STRIDE 129
#define AS_STRIDE 68
#define WS_STRIDE 136   // shorts; 272 B rows -> 16 B aligned, banks spread
#define DS_STRIDE 136
#define GEMM_BLOCKS 256    // %8==0: keeps blockIdx&7 parity for bucket roles
#define BUCKET_BLOCKS 1024 // 8 roles x 128
#define BH 64              // nodes per coarse bucket
#define CAP_B 1536         // bucket capacity: mean 1024, sigma 32 -> +16 sigma

typedef __attribute__((ext_vector_type(8))) short short8;
typedef __attribute__((ext_vector_type(4))) float floatx4;
typedef __attribute__((ext_vector_type(4))) unsigned short ushortx4;

__device__ __forceinline__ unsigned short f2bf(float f) {
    unsigned u = __float_as_uint(f);
    u += 0x7fffu + ((u >> 16) & 1u);   // round-to-nearest-even
    return (unsigned short)(u >> 16);
}

// ---------- fused persistent-GEMM + coarse-bucket scatter ----------
// Bucket = dst>>6 (64 nodes). A bucket's record window advances sequentially,
// so each 64B line fills in ~1/128 of the sweep -- short enough to stay
// L2-resident until full (vs r8-r12 per-node rows filling over the whole
// sweep -> ~7x drain amplification). x8 XCD ownership at bucket granularity.
// Record: .x = (dst&63)<<16 | src (needs N<=65536), .y = w bits (fp32).
__global__ __launch_bounds__(256) void gemm_bucket(
    const float* __restrict__ feat, const float* __restrict__ Wm,
    unsigned short* __restrict__ tf,
    const int* __restrict__ src, const int* __restrict__ dst,
    const float* __restrict__ w, int* __restrict__ bcnt,
    int2* __restrict__ brec, int N, int E)
{
    __shared__ unsigned short Ws[128 * WS_STRIDE];  // 34816 B
    __shared__ unsigned short Ds[64 * DS_STRIDE];   // 17408 B

    if (blockIdx.x >= GEMM_BLOCKS) {
        // ---- bucket role: int4 dst scan, bucket-granular XCD ownership ----
        const int hb = blockIdx.x - GEMM_BLOCKS;
        const int role = hb & 7;
        const int blk = hb >> 3;
        const int nblk = BUCKET_BLOCKS >> 3;
        const int E4 = E & ~3;
        for (int e4 = (blk * 256 + threadIdx.x) * 4; e4 < E4; e4 += nblk * 256 * 4) {
            const int4 d4 = *reinterpret_cast<const int4*>(dst + e4);
#pragma unroll
            for (int j = 0; j < 4; ++j) {
                int d = (j == 0) ? d4.x : (j == 1) ? d4.y : (j == 2) ? d4.z : d4.w;
                int b = d >> 6;
                if ((b & 7) == role) {
                    int e = e4 + j;
                    int pos = atomicAdd(&bcnt[b], 1);
                    if (pos < CAP_B)
                        brec[(size_t)b * CAP_B + pos] =
                            make_int2(((d & 63) << 16) | src[e], __float_as_int(w[e]));
                }
            }
        }
        // tail (E not multiple of 4): first block of each role
        if (threadIdx.x == 0 && blk == 0) {
            for (int e = E4; e < E; ++e) {
                int d = dst[e];
                int b = d >> 6;
                if ((b & 7) == role) {
                    int pos = atomicAdd(&bcnt[b], 1);
                    if (pos < CAP_B)
                        brec[(size_t)b * CAP_B + pos] =
                            make_int2(((d & 63) << 16) | src[e], __float_as_int(w[e]));
                }
            }
        }
        return;
    }

    // ---- gemm role (r12 structure, measured-good) ----
    const int tid = threadIdx.x;
    for (int idx = tid; idx < 128 * 128 / 4; idx += 256) {
        int r = idx >> 5;
        int c = (idx & 31) * 4;
        const float4 v = reinterpret_cast<const float4*>(Wm)[idx];
        ushortx4 s;
        s[0] = f2bf(v.x); s[1] = f2bf(v.y); s[2] = f2bf(v.z); s[3] = f2bf(v.w);
        *reinterpret_cast<ushortx4*>(&Ws[r * WS_STRIDE + c]) = s;
    }
    __syncthreads();

    const int lane = tid & 63;
    const int wave = tid >> 6;
    const int kq = (lane >> 4) * 8;
    const int ntiles = (N + 63) >> 6;

    for (int t = blockIdx.x; t < ntiles; t += GEMM_BLOCKS) {
        const int node0 = t * 64;
        const int mr = node0 + wave * 16 + (lane & 15);
        const float* arow = feat + (size_t)(mr < N ? mr : (N - 1)) * D + kq;

        short8 a[4];
#pragma unroll
        for (int kt = 0; kt < 4; ++kt) {
            const float* p = arow + kt * 32;
            const float4 lo = *reinterpret_cast<const float4*>(p);
            const float4 hi = *reinterpret_cast<const float4*>(p + 4);
            short8 v;
            v[0] = (short)f2bf(lo.x); v[1] = (short)f2bf(lo.y);
            v[2] = (short)f2bf(lo.z); v[3] = (short)f2bf(lo.w);
            v[4] = (short)f2bf(hi.x); v[5] = (short)f2bf(hi.y);
            v[6] = (short)f2bf(hi.z); v[7] = (short)f2bf(hi.w);
            a[kt] = v;
        }

        floatx4 acc[8];
#pragma unroll
        for (int nt = 0; nt < 8; ++nt) {
            acc[nt][0] = 0.f; acc[nt][1] = 0.f; acc[nt][2] = 0.f; acc[nt][3] = 0.f;
        }
#pragma unroll
        for (int nt = 0; nt < 8; ++nt) {
            const unsigned short* brow = &Ws[(nt * 16 + (lane & 15)) * WS_STRIDE + kq];
#pragma unroll
            for (int kt = 0; kt < 4; ++kt) {
                short8 b = *reinterpret_cast<const short8*>(brow + kt * 32);
                acc[nt] = __builtin_amdgcn_mfma_f32_16x16x32_bf16(a[kt], b, acc[nt], 0, 0, 0);
            }
        }

        __syncthreads();
        const int mlocal = wave * 16 + (lane >> 4) * 4;
        const int col = lane & 15;
#pragma unroll
        for (int r = 0; r < 4; ++r) {
            unsigned short* drow = &Ds[(mlocal + r) * DS_STRIDE + col];
#pragma unroll
            for (int nt = 0; nt < 8; ++nt)
                drow[nt * 16] = f2bf(acc[nt][r]);
        }
        __syncthreads();

        for (int idx = tid; idx < 64 * 16; idx += 256) {
            int row = idx >> 4;
            int chunk = idx & 15;
            int m = node0 + row;
            if (m < N) {
                uint4 v = *reinterpret_cast<const uint4*>(&Ds[row * DS_STRIDE + chunk * 8]);
                *reinterpret_cast<uint4*>(tf + (size_t)m * D + chunk * 8) = v;
            }
        }
    }
}

// ---------- pass B: per-bucket LDS aggregation + bias + relu ----------
// Block per bucket. Records stride-partitioned across the 4 waves
// (i = wave, step 16, 4-record unroll into NAMED registers -- r13's
// dynamically-indexed rbuf[]/q[] spilled to scratch: 195 MB WRITE, 517 us).
// One record = one wave: 64 lanes x 4B = coalesced 256B tf-row read;
// accumulate via LDS atomicAdd (ds_add_f32) -- safe for any dloc collision.
__global__ __launch_bounds__(256) void bucket_aggregate(
    const unsigned short* __restrict__ tf, const int2* __restrict__ brec,
    const int* __restrict__ bcnt, const float* __restrict__ bias,
    float* __restrict__ out, int N)
{
    __shared__ float acc[BH * D];   // 32 KB

    const int tid = threadIdx.x;
    const int b = blockIdx.x;
    const int node0 = b * BH;

    for (int i = tid; i < BH * D / 4; i += 256) {
        float4 z; z.x = 0.f; z.y = 0.f; z.z = 0.f; z.w = 0.f;
        reinterpret_cast<float4*>(acc)[i] = z;
    }
    __syncthreads();

    int nrec = bcnt[b];
    nrec = nrec < CAP_B ? nrec : CAP_B;
    const int2* recs = brec + (size_t)b * CAP_B;

    const int wave = tid >> 6;
    const int lane = tid & 63;
    const int c2 = lane * 2;       // this lane's column pair

#define PROC(R, Q)                                                        \
    {                                                                     \
        float wj = __int_as_float((R).y);                                 \
        int dl = ((unsigned)(R).x >> 16) & 63u;                           \
        atomicAdd(&acc[dl * D + c2],     __uint_as_float((Q) << 16) * wj);\
        atomicAdd(&acc[dl * D + c2 + 1],                                  \
                  __uint_as_float((Q) & 0xffff0000u) * wj);               \
    }

    int i = wave;
    for (; i + 12 < nrec; i += 16) {
        int2 r0 = recs[i];
        int2 r1 = recs[i + 4];
        int2 r2 = recs[i + 8];
        int2 r3 = recs[i + 12];
        unsigned q0 = *reinterpret_cast<const unsigned*>(
            tf + (size_t)((unsigned)r0.x & 0xffffu) * D + c2);
        unsigned q1 = *reinterpret_cast<const unsigned*>(
            tf + (size_t)((unsigned)r1.x & 0xffffu) * D + c2);
        unsigned q2 = *reinterpret_cast<const unsigned*>(
            tf + (size_t)((unsigned)r2.x & 0xffffu) * D + c2);
        unsigned q3 = *reinterpret_cast<const unsigned*>(
            tf + (size_t)((unsigned)r3.x & 0xffffu) * D + c2);
        PROC(r0, q0) PROC(r1, q1) PROC(r2, q2) PROC(r3, q3)
    }
    for (; i < nrec; i += 4) {
        int2 r0 = recs[i];
        unsigned q0 = *reinterpret_cast<const unsigned*>(
            tf + (size_t)((unsigned)r0.x & 0xffffu) * D + c2);
        PROC(r0, q0)
    }
#undef PROC

    __syncthreads();

    // epilogue: out = relu(acc + bias), coalesced float4
    for (int i2 = tid; i2 < BH * D / 4; i2 += 256) {
        int row = i2 >> 5;          // 32 float4 per row
        int c4 = (i2 & 31) * 4;
        int n = node0 + row;
        if (n < N) {
            float4 a = reinterpret_cast<float4*>(acc)[i2];
            const float4 bv = *reinterpret_cast<const float4*>(bias + c4);
            float4 r;
            r.x = fmaxf(a.x + bv.x, 0.f);
            r.y = fmaxf(a.y + bv.y, 0.f);
            r.z = fmaxf(a.z + bv.z, 0.f);
            r.w = fmaxf(a.w + bv.w, 0.f);
            *reinterpret_cast<float4*>(out + (size_t)n * D + c4) = r;
        }
    }
}

// ---------------- tier-1 fallback: atomic scatter + fp32 GEMM ----------------
__global__ __launch_bounds__(256) void edge_scatter(
    const float* __restrict__ feat, const int* __restrict__ src,
    const int* __restrict__ dst, const float* __restrict__ w,
    float* __restrict__ agg, int E)
{
    long long idx = (long long)blockIdx.x * 256 + threadIdx.x;
    int e = (int)(idx >> 5);
    if (e >= E) return;
    int c = ((int)idx & 31) << 2;
    int s = src[e];
    int d = dst[e];
    float wv = w[e];
    const float4 f = *reinterpret_cast<const float4*>(feat + (size_t)s * D + c);
    float* a = agg + (size_t)d * D + c;
    atomicAdd(a + 0, f.x * wv);
    atomicAdd(a + 1, f.y * wv);
    atomicAdd(a + 2, f.z * wv);
    atomicAdd(a + 3, f.w * wv);
}

__global__ __launch_bounds__(256) void node_linear(
    const float* __restrict__ in, const float* __restrict__ Wm,
    const float* __restrict__ bias, float* __restrict__ out, int N)
{
    __shared__ float Bs[64 * BS_STRIDE];
    __shared__ float As[TILE_M * AS_STRIDE];
    const int tid = threadIdx.x;
    const int tx = tid & 15;
    const int ty = tid >> 4;
    const int node0 = blockIdx.x * TILE_M;
    float acc[4][8];
#pragma unroll
    for (int i = 0; i < 4; ++i)
#pragma unroll
        for (int jj = 0; jj < 8; ++jj) acc[i][jj] = 0.0f;
    for (int kh = 0; kh < 2; ++kh) {
        const int kbase = kh * 64;
        for (int i = tid; i < 128 * 64; i += 256) {
            int j = i >> 6, k = i & 63;
            Bs[k * BS_STRIDE + j] = Wm[j * 128 + kbase + k];
        }
        for (int i = tid; i < TILE_M * 64; i += 256) {
            int m = i >> 6, k = i & 63;
            int n = node0 + m;
            As[m * AS_STRIDE + k] = (n < N) ? in[(size_t)n * D + kbase + k] : 0.0f;
        }
        __syncthreads();
        for (int k0 = 0; k0 < 64; k0 += 4) {
            float a[4][4];
#pragma unroll
            for (int i = 0; i < 4; ++i) {
                const float4 v = *reinterpret_cast<const float4*>(&As[(ty * 4 + i) * AS_STRIDE + k0]);
                a[i][0] = v.x; a[i][1] = v.y; a[i][2] = v.z; a[i][3] = v.w;
            }
#pragma unroll
            for (int kk = 0; kk < 4; ++kk) {
                float bv[8];
#pragma unroll
                for (int jj = 0; jj < 8; ++jj) bv[jj] = Bs[(k0 + kk) * BS_STRIDE + tx + 16 * jj];
#pragma unroll
                for (int i = 0; i < 4; ++i)
#pragma unroll
                    for (int jj = 0; jj < 8; ++jj) acc[i][jj] += a[i][kk] * bv[jj];
            }
        }
        __syncthreads();
    }
    float bv[8];
#pragma unroll
    for (int jj = 0; jj < 8; ++jj) bv[jj] = bias[tx + 16 * jj];
#pragma unroll
    for (int i = 0; i < 4; ++i) {
        int n = node0 + ty * 4 + i;
        if (n < N) {
            float* o = out + (size_t)n * D;
#pragma unroll
            for (int jj = 0; jj < 8; ++jj) {
                float v = acc[i][jj] + bv[jj];
                o[tx + 16 * jj] = v > 0.0f ? v : 0.0f;
            }
        }
    }
}

extern "C" void kernel_launch(void* const* d_in, const int* in_sizes, int n_in,
                              void* d_out, int out_size, void* d_ws, size_t ws_size,
                              hipStream_t stream) {
    const float* feat = (const float*)d_in[0];
    const int*   src  = (const int*)d_in[1];
    const int*   dst  = (const int*)d_in[2];
    const float* w    = (const float*)d_in[3];
    const float* Wm   = (const float*)d_in[4];
    const float* bias = (const float*)d_in[5];
    float* out = (float*)d_out;

    const int N = in_sizes[0] / D;   // 50000
    const int E = in_sizes[1];       // 800000
    const int NB_C = (N + BH - 1) / BH;   // coarse buckets

    const size_t brec_b = (size_t)NB_C * CAP_B * 8;   // 9.6 MB
    const size_t bcnt_b = (size_t)NB_C * sizeof(int);
    const size_t tf_b   = (size_t)N * D * 2;
    auto align_up = [](size_t x) { return (x + 255) & ~(size_t)255; };

    const size_t need_full = align_up(brec_b) + align_up(bcnt_b) + align_up(tf_b);

    // fast path: src fits 16 bits; bucket capacity ~+16 sigma above mean fill
    if (ws_size >= need_full && N <= 65536 &&
        (long long)E * 2 <= (long long)NB_C * 3 * (CAP_B / 2)) {
        char* p = (char*)d_ws;
        int2* brec = (int2*)p;  p += align_up(brec_b);
        int*  bcnt = (int*)p;   p += align_up(bcnt_b);
        unsigned short* tf = (unsigned short*)p;

        (void)hipMemsetAsync(bcnt, 0, bcnt_b, stream);
        gemm_bucket<<<GEMM_BLOCKS + BUCKET_BLOCKS, 256, 0, stream>>>(
            feat, Wm, tf, src, dst, w, bcnt, brec, N, E);
        bucket_aggregate<<<NB_C, 256, 0, stream>>>(tf, brec, bcnt, bias, out, N);
    } else {
        // fallback: atomic scatter into out, then in-place fp32 linear
        (void)hipMemsetAsync(out, 0, (size_t)N * D * sizeof(float), stream);
        long long st = (long long)E * 32;
        edge_scatter<<<(int)((st + 255) / 256), 256, 0, stream>>>(feat, src, dst, w, out, E);
        node_linear<<<(N + TILE_M - 1) / TILE_M, 256, 0, stream>>>(out, Wm, bias, out, N);
    }
}

// Round 15
// 501.695 us; speedup vs baseline: 2.1163x; 2.1163x over previous
//
#include <hip/hip_runtime.h>

#define D 128
#define TILE_M 64
#define BS_STRIDE 129
#define AS_STRIDE 68
#define WS_STRIDE 136   // shorts; 272 B rows -> 16 B aligned, banks spread
#define DS_STRIDE 136
#define GEMM_BLOCKS 256    // %8==0: keeps blockIdx&7 parity for bucket roles
#define BUCKET_BLOCKS 1024 // 8 roles x 128
#define BH 64              // nodes per coarse bucket
#define CAP_B 1536         // bucket capacity: mean 1024, sigma 32 -> +16 sigma

typedef __attribute__((ext_vector_type(8))) short short8;
typedef __attribute__((ext_vector_type(4))) float floatx4;
typedef __attribute__((ext_vector_type(4))) unsigned short ushortx4;

__device__ __forceinline__ unsigned short f2bf(float f) {
    unsigned u = __float_as_uint(f);
    u += 0x7fffu + ((u >> 16) & 1u);   // round-to-nearest-even
    return (unsigned short)(u >> 16);
}

// ---------- fused persistent-GEMM + coarse-bucket scatter ----------
// Bucket = dst>>6 (64 nodes). A bucket's record window advances sequentially,
// so each 64B line fills in ~1/128 of the sweep -- short enough to stay
// L2-resident until full (vs r8-r12 per-node rows filling over the whole
// sweep -> ~7x drain amplification). x8 XCD ownership at bucket granularity.
// Record: .x = (dst&63)<<16 | src (needs N<=65536), .y = w bits (fp32).
__global__ __launch_bounds__(256) void gemm_bucket(
    const float* __restrict__ feat, const float* __restrict__ Wm,
    unsigned short* __restrict__ tf,
    const int* __restrict__ src, const int* __restrict__ dst,
    const float* __restrict__ w, int* __restrict__ bcnt,
    int2* __restrict__ brec, int N, int E)
{
    __shared__ unsigned short Ws[128 * WS_STRIDE];  // 34816 B
    __shared__ unsigned short Ds[64 * DS_STRIDE];   // 17408 B

    if (blockIdx.x >= GEMM_BLOCKS) {
        // ---- bucket role: int4 dst scan, bucket-granular XCD ownership ----
        const int hb = blockIdx.x - GEMM_BLOCKS;
        const int role = hb & 7;
        const int blk = hb >> 3;
        const int nblk = BUCKET_BLOCKS >> 3;
        const int E4 = E & ~3;
        for (int e4 = (blk * 256 + threadIdx.x) * 4; e4 < E4; e4 += nblk * 256 * 4) {
            const int4 d4 = *reinterpret_cast<const int4*>(dst + e4);
#pragma unroll
            for (int j = 0; j < 4; ++j) {
                int d = (j == 0) ? d4.x : (j == 1) ? d4.y : (j == 2) ? d4.z : d4.w;
                int b = d >> 6;
                if ((b & 7) == role) {
                    int e = e4 + j;
                    int pos = atomicAdd(&bcnt[b], 1);
                    if (pos < CAP_B)
                        brec[(size_t)b * CAP_B + pos] =
                            make_int2(((d & 63) << 16) | src[e], __float_as_int(w[e]));
                }
            }
        }
        // tail (E not multiple of 4): first block of each role
        if (threadIdx.x == 0 && blk == 0) {
            for (int e = E4; e < E; ++e) {
                int d = dst[e];
                int b = d >> 6;
                if ((b & 7) == role) {
                    int pos = atomicAdd(&bcnt[b], 1);
                    if (pos < CAP_B)
                        brec[(size_t)b * CAP_B + pos] =
                            make_int2(((d & 63) << 16) | src[e], __float_as_int(w[e]));
                }
            }
        }
        return;
    }

    // ---- gemm role (r12 structure, measured-good) ----
    const int tid = threadIdx.x;
    for (int idx = tid; idx < 128 * 128 / 4; idx += 256) {
        int r = idx >> 5;
        int c = (idx & 31) * 4;
        const float4 v = reinterpret_cast<const float4*>(Wm)[idx];
        ushortx4 s;
        s[0] = f2bf(v.x); s[1] = f2bf(v.y); s[2] = f2bf(v.z); s[3] = f2bf(v.w);
        *reinterpret_cast<ushortx4*>(&Ws[r * WS_STRIDE + c]) = s;
    }
    __syncthreads();

    const int lane = tid & 63;
    const int wave = tid >> 6;
    const int kq = (lane >> 4) * 8;
    const int ntiles = (N + 63) >> 6;

    for (int t = blockIdx.x; t < ntiles; t += GEMM_BLOCKS) {
        const int node0 = t * 64;
        const int mr = node0 + wave * 16 + (lane & 15);
        const float* arow = feat + (size_t)(mr < N ? mr : (N - 1)) * D + kq;

        short8 a[4];
#pragma unroll
        for (int kt = 0; kt < 4; ++kt) {
            const float* p = arow + kt * 32;
            const float4 lo = *reinterpret_cast<const float4*>(p);
            const float4 hi = *reinterpret_cast<const float4*>(p + 4);
            short8 v;
            v[0] = (short)f2bf(lo.x); v[1] = (short)f2bf(lo.y);
            v[2] = (short)f2bf(lo.z); v[3] = (short)f2bf(lo.w);
            v[4] = (short)f2bf(hi.x); v[5] = (short)f2bf(hi.y);
            v[6] = (short)f2bf(hi.z); v[7] = (short)f2bf(hi.w);
            a[kt] = v;
        }

        floatx4 acc[8];
#pragma unroll
        for (int nt = 0; nt < 8; ++nt) {
            acc[nt][0] = 0.f; acc[nt][1] = 0.f; acc[nt][2] = 0.f; acc[nt][3] = 0.f;
        }
#pragma unroll
        for (int nt = 0; nt < 8; ++nt) {
            const unsigned short* brow = &Ws[(nt * 16 + (lane & 15)) * WS_STRIDE + kq];
#pragma unroll
            for (int kt = 0; kt < 4; ++kt) {
                short8 b = *reinterpret_cast<const short8*>(brow + kt * 32);
                acc[nt] = __builtin_amdgcn_mfma_f32_16x16x32_bf16(a[kt], b, acc[nt], 0, 0, 0);
            }
        }

        __syncthreads();
        const int mlocal = wave * 16 + (lane >> 4) * 4;
        const int col = lane & 15;
#pragma unroll
        for (int r = 0; r < 4; ++r) {
            unsigned short* drow = &Ds[(mlocal + r) * DS_STRIDE + col];
#pragma unroll
            for (int nt = 0; nt < 8; ++nt)
                drow[nt * 16] = f2bf(acc[nt][r]);
        }
        __syncthreads();

        for (int idx = tid; idx < 64 * 16; idx += 256) {
            int row = idx >> 4;
            int chunk = idx & 15;
            int m = node0 + row;
            if (m < N) {
                uint4 v = *reinterpret_cast<const uint4*>(&Ds[row * DS_STRIDE + chunk * 8]);
                *reinterpret_cast<uint4*>(tf + (size_t)m * D + chunk * 8) = v;
            }
        }
    }
}

// ---------- pass B: per-bucket LDS aggregation, race-free by ownership ----------
// 2 wave-pairs; pair p owns private accumulator acc[p] (2x32KB = 64KB) and
// records [p*nrec/2, ...). Within a pair, wave-half h owns columns
// [h*64, h*64+64), lane owns one column -> every (acc, dl, col) cell has
// exactly ONE writer: plain ds ops, NO atomics (r14: f32 LDS atomicAdd
// serialized -> 685 us), NO dynamically-indexed arrays (r13: scratch spill).
// Bank pattern = lane%32 -> 2-way = free. 8-record unroll, named registers.
__global__ __launch_bounds__(256) void bucket_aggregate(
    const unsigned short* __restrict__ tf, const int2* __restrict__ brec,
    const int* __restrict__ bcnt, const float* __restrict__ bias,
    float* __restrict__ out, int N)
{
    __shared__ float acc[2][BH * D];   // 65536 B

    const int tid = threadIdx.x;
    const int wave = tid >> 6;
    const int lane = tid & 63;
    const int pair = wave >> 1;
    const int col = (wave & 1) * 64 + lane;
    const int b = blockIdx.x;
    const int node0 = b * BH;

    for (int i = tid; i < BH * D / 4; i += 256) {
        float4 z; z.x = 0.f; z.y = 0.f; z.z = 0.f; z.w = 0.f;
        reinterpret_cast<float4*>(acc[0])[i] = z;
        reinterpret_cast<float4*>(acc[1])[i] = z;
    }
    __syncthreads();

    int nrec = bcnt[b];
    nrec = nrec < CAP_B ? nrec : CAP_B;
    const int per = (nrec + 1) >> 1;
    const int i0 = pair * per;
    const int i1 = (i0 + per < nrec) ? (i0 + per) : nrec;
    const int2* recs = brec + (size_t)b * CAP_B;
    float* aw = acc[pair];

#define LOADQ(R) __uint_as_float((unsigned)tf[(size_t)((unsigned)(R).x & 0xffffu) * D + col] << 16)
#define STEP(R, V)                                         \
    {                                                      \
        float wj = __int_as_float((R).y);                  \
        int dl = (int)(((unsigned)(R).x >> 16) & 63u);     \
        aw[dl * D + col] += (V) * wj;                      \
    }

    int i = i0;
    for (; i + 7 < i1; i += 8) {
        int2 r0 = recs[i + 0], r1 = recs[i + 1], r2 = recs[i + 2], r3 = recs[i + 3];
        int2 r4 = recs[i + 4], r5 = recs[i + 5], r6 = recs[i + 6], r7 = recs[i + 7];
        float v0 = LOADQ(r0); float v1 = LOADQ(r1);
        float v2 = LOADQ(r2); float v3 = LOADQ(r3);
        float v4 = LOADQ(r4); float v5 = LOADQ(r5);
        float v6 = LOADQ(r6); float v7 = LOADQ(r7);
        STEP(r0, v0) STEP(r1, v1) STEP(r2, v2) STEP(r3, v3)
        STEP(r4, v4) STEP(r5, v5) STEP(r6, v6) STEP(r7, v7)
    }
    for (; i < i1; ++i) {
        int2 r0 = recs[i];
        float v0 = LOADQ(r0);
        STEP(r0, v0)
    }
#undef LOADQ
#undef STEP

    __syncthreads();

    // epilogue: out = relu(acc[0] + acc[1] + bias), coalesced float4
    for (int i2 = tid; i2 < BH * D / 4; i2 += 256) {
        int row = i2 >> 5;          // 32 float4 per row
        int c4 = (i2 & 31) * 4;
        int n = node0 + row;
        if (n < N) {
            float4 a0 = reinterpret_cast<float4*>(acc[0])[i2];
            float4 a1 = reinterpret_cast<float4*>(acc[1])[i2];
            const float4 bv = *reinterpret_cast<const float4*>(bias + c4);
            float4 r;
            r.x = fmaxf(a0.x + a1.x + bv.x, 0.f);
            r.y = fmaxf(a0.y + a1.y + bv.y, 0.f);
            r.z = fmaxf(a0.z + a1.z + bv.z, 0.f);
            r.w = fmaxf(a0.w + a1.w + bv.w, 0.f);
            *reinterpret_cast<float4*>(out + (size_t)n * D + c4) = r;
        }
    }
}

// ---------------- tier-1 fallback: atomic scatter + fp32 GEMM ----------------
__global__ __launch_bounds__(256) void edge_scatter(
    const float* __restrict__ feat, const int* __restrict__ src,
    const int* __restrict__ dst, const float* __restrict__ w,
    float* __restrict__ agg, int E)
{
    long long idx = (long long)blockIdx.x * 256 + threadIdx.x;
    int e = (int)(idx >> 5);
    if (e >= E) return;
    int c = ((int)idx & 31) << 2;
    int s = src[e];
    int d = dst[e];
    float wv = w[e];
    const float4 f = *reinterpret_cast<const float4*>(feat + (size_t)s * D + c);
    float* a = agg + (size_t)d * D + c;
    atomicAdd(a + 0, f.x * wv);
    atomicAdd(a + 1, f.y * wv);
    atomicAdd(a + 2, f.z * wv);
    atomicAdd(a + 3, f.w * wv);
}

__global__ __launch_bounds__(256) void node_linear(
    const float* __restrict__ in, const float* __restrict__ Wm,
    const float* __restrict__ bias, float* __restrict__ out, int N)
{
    __shared__ float Bs[64 * BS_STRIDE];
    __shared__ float As[TILE_M * AS_STRIDE];
    const int tid = threadIdx.x;
    const int tx = tid & 15;
    const int ty = tid >> 4;
    const int node0 = blockIdx.x * TILE_M;
    float acc[4][8];
#pragma unroll
    for (int i = 0; i < 4; ++i)
#pragma unroll
        for (int jj = 0; jj < 8; ++jj) acc[i][jj] = 0.0f;
    for (int kh = 0; kh < 2; ++kh) {
        const int kbase = kh * 64;
        for (int i = tid; i < 128 * 64; i += 256) {
            int j = i >> 6, k = i & 63;
            Bs[k * BS_STRIDE + j] = Wm[j * 128 + kbase + k];
        }
        for (int i = tid; i < TILE_M * 64; i += 256) {
            int m = i >> 6, k = i & 63;
            int n = node0 + m;
            As[m * AS_STRIDE + k] = (n < N) ? in[(size_t)n * D + kbase + k] : 0.0f;
        }
        __syncthreads();
        for (int k0 = 0; k0 < 64; k0 += 4) {
            float a[4][4];
#pragma unroll
            for (int i = 0; i < 4; ++i) {
                const float4 v = *reinterpret_cast<const float4*>(&As[(ty * 4 + i) * AS_STRIDE + k0]);
                a[i][0] = v.x; a[i][1] = v.y; a[i][2] = v.z; a[i][3] = v.w;
            }
#pragma unroll
            for (int kk = 0; kk < 4; ++kk) {
                float bv[8];
#pragma unroll
                for (int jj = 0; jj < 8; ++jj) bv[jj] = Bs[(k0 + kk) * BS_STRIDE + tx + 16 * jj];
#pragma unroll
                for (int i = 0; i < 4; ++i)
#pragma unroll
                    for (int jj = 0; jj < 8; ++jj) acc[i][jj] += a[i][kk] * bv[jj];
            }
        }
        __syncthreads();
    }
    float bv[8];
#pragma unroll
    for (int jj = 0; jj < 8; ++jj) bv[jj] = bias[tx + 16 * jj];
#pragma unroll
    for (int i = 0; i < 4; ++i) {
        int n = node0 + ty * 4 + i;
        if (n < N) {
            float* o = out + (size_t)n * D;
#pragma unroll
            for (int jj = 0; jj < 8; ++jj) {
                float v = acc[i][jj] + bv[jj];
                o[tx + 16 * jj] = v > 0.0f ? v : 0.0f;
            }
        }
    }
}

extern "C" void kernel_launch(void* const* d_in, const int* in_sizes, int n_in,
                              void* d_out, int out_size, void* d_ws, size_t ws_size,
                              hipStream_t stream) {
    const float* feat = (const float*)d_in[0];
    const int*   src  = (const int*)d_in[1];
    const int*   dst  = (const int*)d_in[2];
    const float* w    = (const float*)d_in[3];
    const float* Wm   = (const float*)d_in[4];
    const float* bias = (const float*)d_in[5];
    float* out = (float*)d_out;

    const int N = in_sizes[0] / D;   // 50000
    const int E = in_sizes[1];       // 800000
    const int NB_C = (N + BH - 1) / BH;   // coarse buckets

    const size_t brec_b = (size_t)NB_C * CAP_B * 8;   // 9.6 MB
    const size_t bcnt_b = (size_t)NB_C * sizeof(int);
    const size_t tf_b   = (size_t)N * D * 2;
    auto align_up = [](size_t x) { return (x + 255) & ~(size_t)255; };

    const size_t need_full = align_up(brec_b) + align_up(bcnt_b) + align_up(tf_b);

    // fast path: src fits 16 bits; bucket capacity ~+16 sigma above mean fill
    if (ws_size >= need_full && N <= 65536 &&
        (long long)E * 2 <= (long long)NB_C * 3 * (CAP_B / 2)) {
        char* p = (char*)d_ws;
        int2* brec = (int2*)p;  p += align_up(brec_b);
        int*  bcnt = (int*)p;   p += align_up(bcnt_b);
        unsigned short* tf = (unsigned short*)p;

        (void)hipMemsetAsync(bcnt, 0, bcnt_b, stream);
        gemm_bucket<<<GEMM_BLOCKS + BUCKET_BLOCKS, 256, 0, stream>>>(
            feat, Wm, tf, src, dst, w, bcnt, brec, N, E);
        bucket_aggregate<<<NB_C, 256, 0, stream>>>(tf, brec, bcnt, bias, out, N);
    } else {
        // fallback: atomic scatter into out, then in-place fp32 linear
        (void)hipMemsetAsync(out, 0, (size_t)N * D * sizeof(float), stream);
        long long st = (long long)E * 32;
        edge_scatter<<<(int)((st + 255) / 256), 256, 0, stream>>>(feat, src, dst, w, out, E);
        node_linear<<<(N + TILE_M - 1) / TILE_M, 256, 0, stream>>>(out, Wm, bias, out, N);
    }
}